// Round 8
// baseline (340.508 us; speedup 1.0000x reference)
//
#include <hip/hip_runtime.h>

#define NN 50000
#define NE 800000
#define NT (NE / 32)

// workspace layout (CSR + wave-reduced key rows)
#define CNT_OFF   0u         // 50000 u32 (200 KB)
#define BASE_OFF  204800u    // 50001 u32
#define PART_OFF  409600u    // 196 u32 scan partials
#define SLOT_OFF  417792u    // 800000 u32 per-edge slot (3.2 MB)
#define SRCW_OFF  3670016u   // 800000 uint2 {src|tgt<<16, w} = 6.4 MB
#define M_OFF     (1u << 24) // partial max key rows: NE x 64 u16 (sparse-touched)
#define WS_NEEDED ((size_t)(1u << 24) + (size_t)NE * 64u * 2u)
#define PB 196               // scan blocks: 196*256 >= NN

typedef __bf16 bf16x8 __attribute__((ext_vector_type(8)));
typedef float f32x16 __attribute__((ext_vector_type(16)));
typedef unsigned short u16x2 __attribute__((ext_vector_type(2)));

union U4 { unsigned u[4]; __bf16 h[8]; bf16x8 v; };
union PKU { unsigned u; u16x2 v; };

__device__ __forceinline__ unsigned pkpair(float a, float b) {
  union { unsigned u; __bf16 h[2]; } r;
  r.h[0] = (__bf16)a; r.h[1] = (__bf16)b;
  return r.u;
}
__device__ __forceinline__ float bflo(unsigned u) { return __uint_as_float(u << 16); }
__device__ __forceinline__ float bfhi(unsigned u) { return __uint_as_float(u & 0xFFFF0000u); }
__device__ __forceinline__ unsigned pkmaxu16(unsigned a, unsigned b) {
  PKU x, y, r; x.u = a; y.u = b;
  r.v = __builtin_elementwise_max(x.v, y.v);  // v_pk_max_u16
  return r.u;
}

// ---- pass 1: count + slot assignment ----
extern "C" __global__ void __launch_bounds__(256)
scatter_kernel(const int* __restrict__ ei, unsigned* __restrict__ cnt,
               unsigned* __restrict__ slot) {
  const int e = blockIdx.x * 256 + threadIdx.x;
  if (e < NE) {
    int t = ei[NE + e];
    t = min(max(t, 0), NN - 1);
    slot[e] = atomicAdd(cnt + t, 1u);
  }
}

// ---- pass 1b-i: per-block sums ----
extern "C" __global__ void __launch_bounds__(256)
scan_a_kernel(const unsigned* __restrict__ cnt, unsigned* __restrict__ partial) {
  __shared__ unsigned wsum[4];
  const int t = threadIdx.x, wv = t >> 6, ln = t & 63;
  const int i = blockIdx.x * 256 + t;
  unsigned v = (i < NN) ? cnt[i] : 0u;
  #pragma unroll
  for (int d = 1; d < 64; d <<= 1) v += (unsigned)__shfl_up((int)v, d) * (ln >= d ? 1u : 0u);
  if (ln == 63) wsum[wv] = v;
  __syncthreads();
  if (t == 0) partial[blockIdx.x] = wsum[0] + wsum[1] + wsum[2] + wsum[3];
}

// ---- pass 1b-ii: merged partial-scan + per-element scan -> base ----
extern "C" __global__ void __launch_bounds__(256)
scan_c_kernel(const unsigned* __restrict__ cnt, const unsigned* __restrict__ partial,
              unsigned* __restrict__ base) {
  __shared__ unsigned pscan[256];
  __shared__ unsigned wsum[4];
  const int t = threadIdx.x, wv = t >> 6, ln = t & 63;
  // phase 1: every block scans the 196 partials locally
  const unsigned pv = (t < PB) ? partial[t] : 0u;
  unsigned s = pv;
  #pragma unroll
  for (int d = 1; d < 64; d <<= 1) s += (unsigned)__shfl_up((int)s, d) * (ln >= d ? 1u : 0u);
  if (ln == 63) wsum[wv] = s;
  __syncthreads();
  unsigned woff = 0;
  #pragma unroll
  for (int k = 0; k < 4; ++k) woff += (k < wv) ? wsum[k] : 0u;
  pscan[t] = woff + s - pv;  // exclusive scan of partials
  if (blockIdx.x == 0 && t == 255) base[NN] = woff + s;  // grand total (== NE)
  __syncthreads();
  const unsigned blockoff = pscan[blockIdx.x];
  // phase 2: scan this block's cnt chunk
  const int i = blockIdx.x * 256 + t;
  const unsigned v = (i < NN) ? cnt[i] : 0u;
  unsigned s2 = v;
  #pragma unroll
  for (int d = 1; d < 64; d <<= 1) s2 += (unsigned)__shfl_up((int)s2, d) * (ln >= d ? 1u : 0u);
  if (ln == 63) wsum[wv] = s2;   // safe: all phase-1 wsum reads completed before barrier above
  __syncthreads();
  unsigned woff2 = 0;
  #pragma unroll
  for (int k = 0; k < 4; ++k) woff2 += (k < wv) ? wsum[k] : 0u;
  if (i < NN) base[i] = blockoff + woff2 + s2 - v;
}

// ---- pass 1c: reorder packed edge records to CSR positions ----
extern "C" __global__ void __launch_bounds__(256)
reorder_kernel(const int* __restrict__ ei, const float* __restrict__ ew,
               const unsigned* __restrict__ base, const unsigned* __restrict__ slot,
               uint2* __restrict__ srcw) {
  const int e = blockIdx.x * 256 + threadIdx.x;
  if (e < NE) {
    const int s = min(max(ei[e], 0), NN - 1);
    const int t = min(max(ei[NE + e], 0), NN - 1);
    const unsigned pos = base[t] + slot[e];
    uint2 rec;
    rec.x = (unsigned)s | ((unsigned)t << 16);   // NN < 2^16
    rec.y = __float_as_uint(ew[e]);
    srcw[pos] = rec;
  }
}

// ---- pass 2: per-edge MLP in CSR order; wave-segmented key-max; leader stores ----
extern "C" __global__ void __launch_bounds__(512, 4)
edge_mlp_kernel(const float* __restrict__ x, const float* __restrict__ w1,
                const float* __restrict__ w2, const float* __restrict__ w3,
                const float* __restrict__ g1, const float* __restrict__ b1,
                const float* __restrict__ g2, const float* __restrict__ b2,
                const float* __restrict__ g3, const float* __restrict__ b3,
                const uint2* __restrict__ srcw,
                unsigned short* __restrict__ pmax) {
  __shared__ unsigned lds_w[8192];  // 32 frags x 64 lanes x 16B = 32 KB
  __shared__ float lds_p[512];      // params: g1|b1 (128 ea), g2|b2|g3|b3 (64 ea)
  const int tid = threadIdx.x;

  // ---- stage w1 (16 frags): slot j <-> k = 16t + 8g + j ----
  #pragma unroll 1
  for (int s = tid; s < 1024; s += 512) {
    const int F = s >> 6, L = s & 63;
    const int t = F >> 1, mt = F & 1;
    const int gg = L >> 5, o = (L & 31) + 32 * mt;
    const float* p = w1 + o * 128 + 16 * t + 8 * gg;
    unsigned* d = &lds_w[(unsigned)(F * 64 + L) * 4u];
    d[0] = pkpair(p[0], p[1]); d[1] = pkpair(p[2], p[3]);
    d[2] = pkpair(p[4], p[5]); d[3] = pkpair(p[6], p[7]);
  }
  // ---- stage w2/w3 (8 frags each): slot j <-> k = 16t + 4g + (j&3) + 8*(j>>2) ----
  #pragma unroll 1
  for (int s = tid; s < 1024; s += 512) {
    const int which = s >> 9, r = s & 511;
    const int F = r >> 6, L = r & 63;
    const int t = F >> 1, mt = F & 1;
    const int gg = L >> 5, o = (L & 31) + 32 * mt;
    const float* W = which ? w3 : w2;
    const float* p = W + o * 64 + 16 * t + 4 * gg;
    unsigned* d = &lds_w[(unsigned)((16 + which * 8 + F) * 64 + L) * 4u];
    d[0] = pkpair(p[0], p[1]); d[1] = pkpair(p[2], p[3]);
    d[2] = pkpair(p[8], p[9]); d[3] = pkpair(p[10], p[11]);
  }
  // ---- stage LN params into LDS ----
  #pragma unroll 1
  for (int s = tid; s < 512; s += 512) {
    float v;
    if (s < 128)      v = g1[s];
    else if (s < 256) v = b1[s - 128];
    else if (s < 320) v = g2[s - 256];
    else if (s < 384) v = b2[s - 320];
    else if (s < 448) v = g3[s - 384];
    else              v = b3[s - 448];
    lds_p[s] = v;
  }
  __syncthreads();

  const int lane = tid & 63;
  const int el = lane & 31;
  const int g = lane >> 5;
  const bf16x8* wfrag = (const bf16x8*)lds_w;

  const int wid = blockIdx.x * 8 + (tid >> 6);
  const int nw = gridDim.x * 8;

  // ---- record prefetch (one tile ahead) ----
  int tile = wid;
  int pvs = 0, pvt = 0; float pw = 0.f;
  if (tile < NT) {
    const uint2 rec = srcw[tile * 32 + el];
    pvs = (int)(rec.x & 0xFFFFu); pvt = (int)(rec.x >> 16); pw = __uint_as_float(rec.y);
  }

  while (tile < NT) {
    asm volatile("" ::: "memory");  // keep per-tile LDS/param reads un-hoisted

    const int p = tile * 32 + el;
    const int vsrc = pvs, vtgt = pvt;
    const float wgt = pw;

    const float* xi = x + (size_t)vtgt * 64 + 8 * g;
    const float* xj = x + (size_t)vsrc * 64 + 8 * g;

    // ---- build m half-row, packed bf16; f32 stats on the fly ----
    unsigned mp[32];
    float sum = 0.f, ssq = 0.f;
    #pragma unroll
    for (int t = 0; t < 4; ++t) {
      float4 a = *(const float4*)(xi + 16 * t);
      float4 b = *(const float4*)(xi + 16 * t + 4);
      float4 c = *(const float4*)(xj + 16 * t);
      float4 d4 = *(const float4*)(xj + 16 * t + 4);
      float lo[8] = {a.x, a.y, a.z, a.w, b.x, b.y, b.z, b.w};
      float up[8] = {wgt * (c.x - a.x), wgt * (c.y - a.y), wgt * (c.z - a.z), wgt * (c.w - a.w),
                     wgt * (d4.x - b.x), wgt * (d4.y - b.y), wgt * (d4.z - b.z), wgt * (d4.w - b.w)};
      #pragma unroll
      for (int pp = 0; pp < 4; ++pp) {
        mp[4 * t + pp] = pkpair(lo[2 * pp], lo[2 * pp + 1]);
        mp[16 + 4 * t + pp] = pkpair(up[2 * pp], up[2 * pp + 1]);
      }
      #pragma unroll
      for (int j = 0; j < 8; ++j) {
        sum += lo[j] + up[j];
        ssq += lo[j] * lo[j] + up[j] * up[j];
      }
    }

    // ---- prefetch records for next tile (overlaps LN/MFMA below) ----
    const int ntile = tile + nw;
    if (ntile < NT) {
      const uint2 rec = srcw[ntile * 32 + el];
      pvs = (int)(rec.x & 0xFFFFu); pvt = (int)(rec.x >> 16); pw = __uint_as_float(rec.y);
    }

    sum += __shfl_xor(sum, 32);
    ssq += __shfl_xor(ssq, 32);
    const float mean1 = sum * (1.f / 128.f);
    const float rstd1 = rsqrtf(ssq * (1.f / 128.f) - mean1 * mean1 + 1e-5f);
    const float c01 = -mean1 * rstd1;

    // ---- LN1 affine + LeakyReLU -> B1 frags ----
    U4 B1[8];
    #pragma unroll
    for (int t = 0; t < 8; ++t) {
      const int kb = ((t < 4) ? 16 * t : 64 + 16 * (t - 4)) + 8 * g;
      float4 ga = *(const float4*)(lds_p + kb);
      float4 gb = *(const float4*)(lds_p + kb + 4);
      float4 ba = *(const float4*)(lds_p + 128 + kb);
      float4 bb = *(const float4*)(lds_p + 128 + kb + 4);
      float gv[8] = {ga.x, ga.y, ga.z, ga.w, gb.x, gb.y, gb.z, gb.w};
      float bv[8] = {ba.x, ba.y, ba.z, ba.w, bb.x, bb.y, bb.z, bb.w};
      #pragma unroll
      for (int pp = 0; pp < 4; ++pp) {
        const unsigned u = mp[4 * t + pp];
        float v0 = fmaf(bflo(u), rstd1, c01);
        float v1 = fmaf(bfhi(u), rstd1, c01);
        v0 = fmaf(v0, gv[2 * pp], bv[2 * pp]);
        v1 = fmaf(v1, gv[2 * pp + 1], bv[2 * pp + 1]);
        v0 = fmaxf(v0, 0.2f * v0);
        v1 = fmaxf(v1, 0.2f * v1);
        B1[t].h[2 * pp] = (__bf16)v0;
        B1[t].h[2 * pp + 1] = (__bf16)v1;
      }
    }

    // ---- stage 1 (accumulators A0/A1, reused by all 3 stages) ----
    f32x16 A0, A1;
    #pragma unroll
    for (int i = 0; i < 16; ++i) { A0[i] = 0.f; A1[i] = 0.f; }
    #pragma unroll
    for (int t = 0; t < 8; ++t) {
      A0 = __builtin_amdgcn_mfma_f32_32x32x16_bf16(wfrag[(2 * t + 0) * 64 + lane], B1[t].v, A0, 0, 0, 0);
      A1 = __builtin_amdgcn_mfma_f32_32x32x16_bf16(wfrag[(2 * t + 1) * 64 + lane], B1[t].v, A1, 0, 0, 0);
    }

    // ---- LN2 -> B2 ----
    float s2 = 0.f, q2 = 0.f;
    #pragma unroll
    for (int i = 0; i < 16; ++i) {
      s2 += A0[i] + A1[i];
      q2 += A0[i] * A0[i] + A1[i] * A1[i];
    }
    s2 += __shfl_xor(s2, 32); q2 += __shfl_xor(q2, 32);
    const float mean2 = s2 * (1.f / 64.f);
    const float rstd2 = rsqrtf(q2 * (1.f / 64.f) - mean2 * mean2 + 1e-5f);
    const float c02 = -mean2 * rstd2;

    U4 B2[4];
    #pragma unroll
    for (int t2 = 0; t2 < 4; ++t2) {
      const int kb = 16 * t2 + 4 * g;
      float4 gA = *(const float4*)(lds_p + 256 + kb);
      float4 gB = *(const float4*)(lds_p + 256 + kb + 8);
      float4 bA = *(const float4*)(lds_p + 320 + kb);
      float4 bB = *(const float4*)(lds_p + 320 + kb + 8);
      float gv[8] = {gA.x, gA.y, gA.z, gA.w, gB.x, gB.y, gB.z, gB.w};
      float bv[8] = {bA.x, bA.y, bA.z, bA.w, bB.x, bB.y, bB.z, bB.w};
      #pragma unroll
      for (int j = 0; j < 8; ++j) {
        const int reg = 4 * (2 * (t2 & 1) + (j >> 2)) + (j & 3);
        float v = (t2 >> 1) ? A1[reg] : A0[reg];
        v = fmaf(v, rstd2, c02);
        v = fmaf(v, gv[j], bv[j]);
        v = fmaxf(v, 0.2f * v);
        B2[t2].h[j] = (__bf16)v;
      }
    }

    // ---- stage 2 (reuse A0/A1) ----
    #pragma unroll
    for (int i = 0; i < 16; ++i) { A0[i] = 0.f; A1[i] = 0.f; }
    #pragma unroll
    for (int t2 = 0; t2 < 4; ++t2) {
      A0 = __builtin_amdgcn_mfma_f32_32x32x16_bf16(wfrag[(16 + 2 * t2 + 0) * 64 + lane], B2[t2].v, A0, 0, 0, 0);
      A1 = __builtin_amdgcn_mfma_f32_32x32x16_bf16(wfrag[(16 + 2 * t2 + 1) * 64 + lane], B2[t2].v, A1, 0, 0, 0);
    }

    // ---- LN3 -> B3 ----
    float s3 = 0.f, q3 = 0.f;
    #pragma unroll
    for (int i = 0; i < 16; ++i) {
      s3 += A0[i] + A1[i];
      q3 += A0[i] * A0[i] + A1[i] * A1[i];
    }
    s3 += __shfl_xor(s3, 32); q3 += __shfl_xor(q3, 32);
    const float mean3 = s3 * (1.f / 64.f);
    const float rstd3 = rsqrtf(q3 * (1.f / 64.f) - mean3 * mean3 + 1e-5f);
    const float c03 = -mean3 * rstd3;

    U4 B3[4];
    #pragma unroll
    for (int t2 = 0; t2 < 4; ++t2) {
      const int kb = 16 * t2 + 4 * g;
      float4 gA = *(const float4*)(lds_p + 384 + kb);
      float4 gB = *(const float4*)(lds_p + 384 + kb + 8);
      float4 bA = *(const float4*)(lds_p + 448 + kb);
      float4 bB = *(const float4*)(lds_p + 448 + kb + 8);
      float gv[8] = {gA.x, gA.y, gA.z, gA.w, gB.x, gB.y, gB.z, gB.w};
      float bv[8] = {bA.x, bA.y, bA.z, bA.w, bB.x, bB.y, bB.z, bB.w};
      #pragma unroll
      for (int j = 0; j < 8; ++j) {
        const int reg = 4 * (2 * (t2 & 1) + (j >> 2)) + (j & 3);
        float v = (t2 >> 1) ? A1[reg] : A0[reg];
        v = fmaf(v, rstd3, c03);
        v = fmaf(v, gv[j], bv[j]);
        v = fmaxf(v, 0.2f * v);
        B3[t2].h[j] = (__bf16)v;
      }
    }

    // ---- stage 3 (reuse A0/A1) ----
    #pragma unroll
    for (int i = 0; i < 16; ++i) { A0[i] = 0.f; A1[i] = 0.f; }
    #pragma unroll
    for (int t2 = 0; t2 < 4; ++t2) {
      A0 = __builtin_amdgcn_mfma_f32_32x32x16_bf16(wfrag[(24 + 2 * t2 + 0) * 64 + lane], B3[t2].v, A0, 0, 0, 0);
      A1 = __builtin_amdgcn_mfma_f32_32x32x16_bf16(wfrag[(24 + 2 * t2 + 1) * 64 + lane], B3[t2].v, A1, 0, 0, 0);
    }

    // ---- pack results to bf16 pairs, then encode order-preserving u16 keys ----
    unsigned P[16];
    #pragma unroll
    for (int q = 0; q < 4; ++q) {
      P[2 * q + 0] = pkpair(A0[4 * q + 0], A0[4 * q + 1]);
      P[2 * q + 1] = pkpair(A0[4 * q + 2], A0[4 * q + 3]);
      P[8 + 2 * q + 0] = pkpair(A1[4 * q + 0], A1[4 * q + 1]);
      P[8 + 2 * q + 1] = pkpair(A1[4 * q + 2], A1[4 * q + 3]);
    }
    // key = u ^ (sign ? 0xFFFF : 0x8000) per 16-bit half (monotone map)
    #pragma unroll
    for (int i = 0; i < 16; ++i) {
      const unsigned u = P[i];
      const unsigned tt = (u >> 15) & 0x00010001u;
      P[i] = u ^ ((tt << 15) - tt + 0x80008000u);
    }
    // ---- segmented suffix-max across el (positions sorted by vtgt) ----
    #pragma unroll
    for (int d = 1; d < 32; d <<= 1) {
      const int ot = __shfl_down(vtgt, d, 32);
      const bool mrg = (ot == vtgt);
      #pragma unroll
      for (int i = 0; i < 16; ++i) {
        const unsigned pv = __shfl_down(P[i], d, 32);
        const unsigned mx = pkmaxu16(P[i], pv);
        P[i] = mrg ? mx : P[i];
      }
    }
    // ---- run-leader stores one partial key row at position p ----
    const int pt = __shfl_up(vtgt, 1, 32);
    if (el == 0 || pt != vtgt) {
      unsigned short* row = pmax + (size_t)p * 64;
      #pragma unroll
      for (int q = 0; q < 4; ++q) {
        uint2 lo; lo.x = P[2 * q]; lo.y = P[2 * q + 1];
        uint2 hi; hi.x = P[8 + 2 * q]; hi.y = P[8 + 2 * q + 1];
        *(uint2*)(row + 8 * q + 4 * g) = lo;
        *(uint2*)(row + 32 + 8 * q + 4 * g) = hi;
      }
    }

    tile = ntile;
  }
}

// ---- pass 3: per-node key-max + decode + residual ----
extern "C" __global__ void __launch_bounds__(256)
gather_max_kernel(const float* __restrict__ x, const unsigned short* __restrict__ pmax,
                  const unsigned* __restrict__ base, float* __restrict__ out) {
  const int node = blockIdx.x * 4 + (threadIdx.x >> 6);
  const int lane = threadIdx.x & 63;
  if (node >= NN) return;

  const unsigned b0 = base[node];
  const unsigned b1 = base[node + 1];
  float maxv = 0.f;
  if (b1 > b0) {
    // partial key rows live at position b0 and at each 32-boundary inside (b0, b1)
    unsigned kmax = pmax[(size_t)b0 * 64 + lane];
    const unsigned k1 = (b1 - 1) >> 5;
    for (unsigned k = (b0 >> 5) + 1; k <= k1; ++k) {
      kmax = max(kmax, (unsigned)pmax[((size_t)k << 5) * 64 + lane]);
    }
    // decode monotone key -> bf16 bits
    const unsigned orig = (kmax & 0x8000u) ? (kmax ^ 0x8000u) : (~kmax & 0xFFFFu);
    maxv = __uint_as_float(orig << 16);
  }
  const size_t o = (size_t)node * 64 + lane;
  out[o] = maxv + x[o];
}

extern "C" void kernel_launch(void* const* d_in, const int* in_sizes, int n_in,
                              void* d_out, int out_size, void* d_ws, size_t ws_size,
                              hipStream_t stream) {
  (void)in_sizes; (void)n_in; (void)out_size; (void)ws_size;
  const float* x  = (const float*)d_in[0];
  const float* ew = (const float*)d_in[1];
  const int*   ei = (const int*)d_in[2];
  const float* w1 = (const float*)d_in[3];
  const float* w2 = (const float*)d_in[4];
  const float* w3 = (const float*)d_in[5];
  const float* g1 = (const float*)d_in[6];
  const float* b1 = (const float*)d_in[7];
  const float* g2 = (const float*)d_in[8];
  const float* b2 = (const float*)d_in[9];
  const float* g3 = (const float*)d_in[10];
  const float* b3 = (const float*)d_in[11];

  unsigned* cnt  = (unsigned*)((char*)d_ws + CNT_OFF);
  unsigned* base = (unsigned*)((char*)d_ws + BASE_OFF);
  unsigned* part = (unsigned*)((char*)d_ws + PART_OFF);
  unsigned* slot = (unsigned*)((char*)d_ws + SLOT_OFF);
  uint2*    srcw = (uint2*)((char*)d_ws + SRCW_OFF);
  unsigned short* pmax = (unsigned short*)((char*)d_ws + M_OFF);

  hipMemsetAsync(cnt, 0, (size_t)NN * sizeof(unsigned), stream);
  scatter_kernel<<<(NE + 255) / 256, 256, 0, stream>>>(ei, cnt, slot);
  scan_a_kernel<<<PB, 256, 0, stream>>>(cnt, part);
  scan_c_kernel<<<PB, 256, 0, stream>>>(cnt, part, base);
  reorder_kernel<<<(NE + 255) / 256, 256, 0, stream>>>(ei, ew, base, slot, srcw);
  edge_mlp_kernel<<<1024, 512, 0, stream>>>(x, w1, w2, w3,
                                            g1, b1, g2, b2, g3, b3,
                                            srcw, pmax);
  gather_max_kernel<<<(NN + 3) / 4, 256, 0, stream>>>(x, pmax, base, (float*)d_out);
}

// Round 9
// 277.289 us; speedup vs baseline: 1.2280x; 1.2280x over previous
//
#include <hip/hip_runtime.h>

#define NN 50000
#define NE 800000
#define NT (NE / 32)

// workspace layout (CSR + wave-reduced key rows)
#define CNT_OFF   0u         // 50000 u32 (200 KB)
#define BASE_OFF  204800u    // 50001 u32
#define PART_OFF  409600u    // 196 u32 scan partials
#define SLOT_OFF  417792u    // 800000 u32 per-edge slot (3.2 MB)
#define SRCW_OFF  3670016u   // 800000 uint2 {src|tgt<<16, w} = 6.4 MB
#define M_OFF     (1u << 24) // partial max key rows: NE x 64 u16 (sparse-touched)
#define WS_NEEDED ((size_t)(1u << 24) + (size_t)NE * 64u * 2u)
#define PB 196               // scan blocks: 196*256 >= NN

typedef __bf16 bf16x8 __attribute__((ext_vector_type(8)));
typedef float f32x16 __attribute__((ext_vector_type(16)));
typedef unsigned short u16x2 __attribute__((ext_vector_type(2)));

union U4 { unsigned u[4]; __bf16 h[8]; bf16x8 v; };
union PKU { unsigned u; u16x2 v; };

__device__ __forceinline__ unsigned pkpair(float a, float b) {
  union { unsigned u; __bf16 h[2]; } r;
  r.h[0] = (__bf16)a; r.h[1] = (__bf16)b;
  return r.u;
}
__device__ __forceinline__ float bflo(unsigned u) { return __uint_as_float(u << 16); }
__device__ __forceinline__ float bfhi(unsigned u) { return __uint_as_float(u & 0xFFFF0000u); }
__device__ __forceinline__ unsigned pkmaxu16(unsigned a, unsigned b) {
  PKU x, y, r; x.u = a; y.u = b;
  r.v = __builtin_elementwise_max(x.v, y.v);  // v_pk_max_u16
  return r.u;
}

// ---- pass 1: count + slot assignment ----
extern "C" __global__ void __launch_bounds__(256)
scatter_kernel(const int* __restrict__ ei, unsigned* __restrict__ cnt,
               unsigned* __restrict__ slot) {
  const int e = blockIdx.x * 256 + threadIdx.x;
  if (e < NE) {
    int t = ei[NE + e];
    t = min(max(t, 0), NN - 1);
    slot[e] = atomicAdd(cnt + t, 1u);
  }
}

// ---- pass 1b-i: per-block sums ----
extern "C" __global__ void __launch_bounds__(256)
scan_a_kernel(const unsigned* __restrict__ cnt, unsigned* __restrict__ partial) {
  __shared__ unsigned wsum[4];
  const int t = threadIdx.x, wv = t >> 6, ln = t & 63;
  const int i = blockIdx.x * 256 + t;
  unsigned v = (i < NN) ? cnt[i] : 0u;
  #pragma unroll
  for (int d = 1; d < 64; d <<= 1) v += (unsigned)__shfl_up((int)v, d) * (ln >= d ? 1u : 0u);
  if (ln == 63) wsum[wv] = v;
  __syncthreads();
  if (t == 0) partial[blockIdx.x] = wsum[0] + wsum[1] + wsum[2] + wsum[3];
}

// ---- pass 1b-ii: merged partial-scan + per-element scan -> base ----
extern "C" __global__ void __launch_bounds__(256)
scan_c_kernel(const unsigned* __restrict__ cnt, const unsigned* __restrict__ partial,
              unsigned* __restrict__ base) {
  __shared__ unsigned pscan[256];
  __shared__ unsigned wsum[4];
  const int t = threadIdx.x, wv = t >> 6, ln = t & 63;
  // phase 1: every block scans the 196 partials locally
  const unsigned pv = (t < PB) ? partial[t] : 0u;
  unsigned s = pv;
  #pragma unroll
  for (int d = 1; d < 64; d <<= 1) s += (unsigned)__shfl_up((int)s, d) * (ln >= d ? 1u : 0u);
  if (ln == 63) wsum[wv] = s;
  __syncthreads();
  unsigned woff = 0;
  #pragma unroll
  for (int k = 0; k < 4; ++k) woff += (k < wv) ? wsum[k] : 0u;
  pscan[t] = woff + s - pv;  // exclusive scan of partials
  if (blockIdx.x == 0 && t == 255) base[NN] = woff + s;  // grand total (== NE)
  __syncthreads();
  const unsigned blockoff = pscan[blockIdx.x];
  // phase 2: scan this block's cnt chunk
  const int i = blockIdx.x * 256 + t;
  const unsigned v = (i < NN) ? cnt[i] : 0u;
  unsigned s2 = v;
  #pragma unroll
  for (int d = 1; d < 64; d <<= 1) s2 += (unsigned)__shfl_up((int)s2, d) * (ln >= d ? 1u : 0u);
  if (ln == 63) wsum[wv] = s2;
  __syncthreads();
  unsigned woff2 = 0;
  #pragma unroll
  for (int k = 0; k < 4; ++k) woff2 += (k < wv) ? wsum[k] : 0u;
  if (i < NN) base[i] = blockoff + woff2 + s2 - v;
}

// ---- pass 1c: reorder packed edge records to CSR positions ----
extern "C" __global__ void __launch_bounds__(256)
reorder_kernel(const int* __restrict__ ei, const float* __restrict__ ew,
               const unsigned* __restrict__ base, const unsigned* __restrict__ slot,
               uint2* __restrict__ srcw) {
  const int e = blockIdx.x * 256 + threadIdx.x;
  if (e < NE) {
    const int s = min(max(ei[e], 0), NN - 1);
    const int t = min(max(ei[NE + e], 0), NN - 1);
    const unsigned pos = base[t] + slot[e];
    uint2 rec;
    rec.x = (unsigned)s | ((unsigned)t << 16);   // NN < 2^16
    rec.y = __float_as_uint(ew[e]);
    srcw[pos] = rec;
  }
}

// ---- pass 2: per-edge MLP in CSR order; wave-segmented key-max; leader stores ----
// 256 threads, min 3 waves/EU: proven no-spill envelope (R7: VGPR 80).
// LDS = exactly 32 KB (weights only) -> 5 blocks/CU (163840/32768); LN params
// come from global (L1-resident, re-read each tile via the memory clobber).
extern "C" __global__ void __launch_bounds__(256, 3)
edge_mlp_kernel(const float* __restrict__ x, const float* __restrict__ w1,
                const float* __restrict__ w2, const float* __restrict__ w3,
                const float* __restrict__ g1, const float* __restrict__ b1,
                const float* __restrict__ g2, const float* __restrict__ b2,
                const float* __restrict__ g3, const float* __restrict__ b3,
                const uint2* __restrict__ srcw,
                unsigned short* __restrict__ pmax) {
  __shared__ unsigned lds_w[8192];  // 32 frags x 64 lanes x 16B = 32768 B exactly
  const int tid = threadIdx.x;

  // ---- stage w1 (16 frags): slot j <-> k = 16t + 8g + j ----
  #pragma unroll 1
  for (int s = tid; s < 1024; s += 256) {
    const int F = s >> 6, L = s & 63;
    const int t = F >> 1, mt = F & 1;
    const int gg = L >> 5, o = (L & 31) + 32 * mt;
    const float* p = w1 + o * 128 + 16 * t + 8 * gg;
    unsigned* d = &lds_w[(unsigned)(F * 64 + L) * 4u];
    d[0] = pkpair(p[0], p[1]); d[1] = pkpair(p[2], p[3]);
    d[2] = pkpair(p[4], p[5]); d[3] = pkpair(p[6], p[7]);
  }
  // ---- stage w2/w3 (8 frags each): slot j <-> k = 16t + 4g + (j&3) + 8*(j>>2) ----
  #pragma unroll 1
  for (int s = tid; s < 1024; s += 256) {
    const int which = s >> 9, r = s & 511;
    const int F = r >> 6, L = r & 63;
    const int t = F >> 1, mt = F & 1;
    const int gg = L >> 5, o = (L & 31) + 32 * mt;
    const float* W = which ? w3 : w2;
    const float* p = W + o * 64 + 16 * t + 4 * gg;
    unsigned* d = &lds_w[(unsigned)((16 + which * 8 + F) * 64 + L) * 4u];
    d[0] = pkpair(p[0], p[1]); d[1] = pkpair(p[2], p[3]);
    d[2] = pkpair(p[8], p[9]); d[3] = pkpair(p[10], p[11]);
  }
  __syncthreads();

  const int lane = tid & 63;
  const int el = lane & 31;
  const int g = lane >> 5;
  const bf16x8* wfrag = (const bf16x8*)lds_w;

  const int wid = blockIdx.x * 4 + (tid >> 6);
  const int nw = gridDim.x * 4;

  // ---- record prefetch (one tile ahead) ----
  int tile = wid;
  int pvs = 0, pvt = 0; float pw = 0.f;
  if (tile < NT) {
    const uint2 rec = srcw[tile * 32 + el];
    pvs = (int)(rec.x & 0xFFFFu); pvt = (int)(rec.x >> 16); pw = __uint_as_float(rec.y);
  }

  while (tile < NT) {
    asm volatile("" ::: "memory");  // keep per-tile LDS/param reads un-hoisted

    const int p = tile * 32 + el;
    const int vsrc = pvs, vtgt = pvt;
    const float wgt = pw;

    const float* xi = x + (size_t)vtgt * 64 + 8 * g;
    const float* xj = x + (size_t)vsrc * 64 + 8 * g;

    // ---- build m half-row, packed bf16; f32 stats on the fly ----
    unsigned mp[32];
    float sum = 0.f, ssq = 0.f;
    #pragma unroll
    for (int t = 0; t < 4; ++t) {
      float4 a = *(const float4*)(xi + 16 * t);
      float4 b = *(const float4*)(xi + 16 * t + 4);
      float4 c = *(const float4*)(xj + 16 * t);
      float4 d4 = *(const float4*)(xj + 16 * t + 4);
      float lo[8] = {a.x, a.y, a.z, a.w, b.x, b.y, b.z, b.w};
      float up[8] = {wgt * (c.x - a.x), wgt * (c.y - a.y), wgt * (c.z - a.z), wgt * (c.w - a.w),
                     wgt * (d4.x - b.x), wgt * (d4.y - b.y), wgt * (d4.z - b.z), wgt * (d4.w - b.w)};
      #pragma unroll
      for (int pp = 0; pp < 4; ++pp) {
        mp[4 * t + pp] = pkpair(lo[2 * pp], lo[2 * pp + 1]);
        mp[16 + 4 * t + pp] = pkpair(up[2 * pp], up[2 * pp + 1]);
      }
      #pragma unroll
      for (int j = 0; j < 8; ++j) {
        sum += lo[j] + up[j];
        ssq += lo[j] * lo[j] + up[j] * up[j];
      }
    }

    // ---- prefetch records for next tile (overlaps LN/MFMA below) ----
    const int ntile = tile + nw;
    if (ntile < NT) {
      const uint2 rec = srcw[ntile * 32 + el];
      pvs = (int)(rec.x & 0xFFFFu); pvt = (int)(rec.x >> 16); pw = __uint_as_float(rec.y);
    }

    sum += __shfl_xor(sum, 32);
    ssq += __shfl_xor(ssq, 32);
    const float mean1 = sum * (1.f / 128.f);
    const float rstd1 = rsqrtf(ssq * (1.f / 128.f) - mean1 * mean1 + 1e-5f);
    const float c01 = -mean1 * rstd1;

    // ---- LN1 affine + LeakyReLU -> B1 frags (params via L1) ----
    U4 B1[8];
    #pragma unroll
    for (int t = 0; t < 8; ++t) {
      const int kb = ((t < 4) ? 16 * t : 64 + 16 * (t - 4)) + 8 * g;
      float4 ga = *(const float4*)(g1 + kb);
      float4 gb = *(const float4*)(g1 + kb + 4);
      float4 ba = *(const float4*)(b1 + kb);
      float4 bb = *(const float4*)(b1 + kb + 4);
      float gv[8] = {ga.x, ga.y, ga.z, ga.w, gb.x, gb.y, gb.z, gb.w};
      float bv[8] = {ba.x, ba.y, ba.z, ba.w, bb.x, bb.y, bb.z, bb.w};
      #pragma unroll
      for (int pp = 0; pp < 4; ++pp) {
        const unsigned u = mp[4 * t + pp];
        float v0 = fmaf(bflo(u), rstd1, c01);
        float v1 = fmaf(bfhi(u), rstd1, c01);
        v0 = fmaf(v0, gv[2 * pp], bv[2 * pp]);
        v1 = fmaf(v1, gv[2 * pp + 1], bv[2 * pp + 1]);
        v0 = fmaxf(v0, 0.2f * v0);
        v1 = fmaxf(v1, 0.2f * v1);
        B1[t].h[2 * pp] = (__bf16)v0;
        B1[t].h[2 * pp + 1] = (__bf16)v1;
      }
    }

    // ---- stage 1 (accumulators A0/A1, reused by all 3 stages) ----
    f32x16 A0, A1;
    #pragma unroll
    for (int i = 0; i < 16; ++i) { A0[i] = 0.f; A1[i] = 0.f; }
    #pragma unroll
    for (int t = 0; t < 8; ++t) {
      A0 = __builtin_amdgcn_mfma_f32_32x32x16_bf16(wfrag[(2 * t + 0) * 64 + lane], B1[t].v, A0, 0, 0, 0);
      A1 = __builtin_amdgcn_mfma_f32_32x32x16_bf16(wfrag[(2 * t + 1) * 64 + lane], B1[t].v, A1, 0, 0, 0);
    }

    // ---- LN2 -> B2 ----
    float s2 = 0.f, q2 = 0.f;
    #pragma unroll
    for (int i = 0; i < 16; ++i) {
      s2 += A0[i] + A1[i];
      q2 += A0[i] * A0[i] + A1[i] * A1[i];
    }
    s2 += __shfl_xor(s2, 32); q2 += __shfl_xor(q2, 32);
    const float mean2 = s2 * (1.f / 64.f);
    const float rstd2 = rsqrtf(q2 * (1.f / 64.f) - mean2 * mean2 + 1e-5f);
    const float c02 = -mean2 * rstd2;

    U4 B2[4];
    #pragma unroll
    for (int t2 = 0; t2 < 4; ++t2) {
      const int kb = 16 * t2 + 4 * g;
      float4 gA = *(const float4*)(g2 + kb);
      float4 gB = *(const float4*)(g2 + kb + 8);
      float4 bA = *(const float4*)(b2 + kb);
      float4 bB = *(const float4*)(b2 + kb + 8);
      float gv[8] = {gA.x, gA.y, gA.z, gA.w, gB.x, gB.y, gB.z, gB.w};
      float bv[8] = {bA.x, bA.y, bA.z, bA.w, bB.x, bB.y, bB.z, bB.w};
      #pragma unroll
      for (int j = 0; j < 8; ++j) {
        const int reg = 4 * (2 * (t2 & 1) + (j >> 2)) + (j & 3);
        float v = (t2 >> 1) ? A1[reg] : A0[reg];
        v = fmaf(v, rstd2, c02);
        v = fmaf(v, gv[j], bv[j]);
        v = fmaxf(v, 0.2f * v);
        B2[t2].h[j] = (__bf16)v;
      }
    }

    // ---- stage 2 (reuse A0/A1) ----
    #pragma unroll
    for (int i = 0; i < 16; ++i) { A0[i] = 0.f; A1[i] = 0.f; }
    #pragma unroll
    for (int t2 = 0; t2 < 4; ++t2) {
      A0 = __builtin_amdgcn_mfma_f32_32x32x16_bf16(wfrag[(16 + 2 * t2 + 0) * 64 + lane], B2[t2].v, A0, 0, 0, 0);
      A1 = __builtin_amdgcn_mfma_f32_32x32x16_bf16(wfrag[(16 + 2 * t2 + 1) * 64 + lane], B2[t2].v, A1, 0, 0, 0);
    }

    // ---- LN3 -> B3 ----
    float s3 = 0.f, q3 = 0.f;
    #pragma unroll
    for (int i = 0; i < 16; ++i) {
      s3 += A0[i] + A1[i];
      q3 += A0[i] * A0[i] + A1[i] * A1[i];
    }
    s3 += __shfl_xor(s3, 32); q3 += __shfl_xor(q3, 32);
    const float mean3 = s3 * (1.f / 64.f);
    const float rstd3 = rsqrtf(q3 * (1.f / 64.f) - mean3 * mean3 + 1e-5f);
    const float c03 = -mean3 * rstd3;

    U4 B3[4];
    #pragma unroll
    for (int t2 = 0; t2 < 4; ++t2) {
      const int kb = 16 * t2 + 4 * g;
      float4 gA = *(const float4*)(g3 + kb);
      float4 gB = *(const float4*)(g3 + kb + 8);
      float4 bA = *(const float4*)(b3 + kb);
      float4 bB = *(const float4*)(b3 + kb + 8);
      float gv[8] = {gA.x, gA.y, gA.z, gA.w, gB.x, gB.y, gB.z, gB.w};
      float bv[8] = {bA.x, bA.y, bA.z, bA.w, bB.x, bB.y, bB.z, bB.w};
      #pragma unroll
      for (int j = 0; j < 8; ++j) {
        const int reg = 4 * (2 * (t2 & 1) + (j >> 2)) + (j & 3);
        float v = (t2 >> 1) ? A1[reg] : A0[reg];
        v = fmaf(v, rstd3, c03);
        v = fmaf(v, gv[j], bv[j]);
        v = fmaxf(v, 0.2f * v);
        B3[t2].h[j] = (__bf16)v;
      }
    }

    // ---- stage 3 (reuse A0/A1) ----
    #pragma unroll
    for (int i = 0; i < 16; ++i) { A0[i] = 0.f; A1[i] = 0.f; }
    #pragma unroll
    for (int t2 = 0; t2 < 4; ++t2) {
      A0 = __builtin_amdgcn_mfma_f32_32x32x16_bf16(wfrag[(24 + 2 * t2 + 0) * 64 + lane], B3[t2].v, A0, 0, 0, 0);
      A1 = __builtin_amdgcn_mfma_f32_32x32x16_bf16(wfrag[(24 + 2 * t2 + 1) * 64 + lane], B3[t2].v, A1, 0, 0, 0);
    }

    // ---- pack results to bf16 pairs, then encode order-preserving u16 keys ----
    unsigned P[16];
    #pragma unroll
    for (int q = 0; q < 4; ++q) {
      P[2 * q + 0] = pkpair(A0[4 * q + 0], A0[4 * q + 1]);
      P[2 * q + 1] = pkpair(A0[4 * q + 2], A0[4 * q + 3]);
      P[8 + 2 * q + 0] = pkpair(A1[4 * q + 0], A1[4 * q + 1]);
      P[8 + 2 * q + 1] = pkpair(A1[4 * q + 2], A1[4 * q + 3]);
    }
    // key = u ^ (sign ? 0xFFFF : 0x8000) per 16-bit half (monotone map)
    #pragma unroll
    for (int i = 0; i < 16; ++i) {
      const unsigned u = P[i];
      const unsigned tt = (u >> 15) & 0x00010001u;
      P[i] = u ^ ((tt << 15) - tt + 0x80008000u);
    }
    // ---- segmented suffix-max across el (positions sorted by vtgt) ----
    #pragma unroll
    for (int d = 1; d < 32; d <<= 1) {
      const int ot = __shfl_down(vtgt, d, 32);
      const bool mrg = (ot == vtgt);
      #pragma unroll
      for (int i = 0; i < 16; ++i) {
        const unsigned pv = __shfl_down(P[i], d, 32);
        const unsigned mx = pkmaxu16(P[i], pv);
        P[i] = mrg ? mx : P[i];
      }
    }
    // ---- run-leader stores one partial key row at position p ----
    const int pt = __shfl_up(vtgt, 1, 32);
    if (el == 0 || pt != vtgt) {
      unsigned short* row = pmax + (size_t)p * 64;
      #pragma unroll
      for (int q = 0; q < 4; ++q) {
        uint2 lo; lo.x = P[2 * q]; lo.y = P[2 * q + 1];
        uint2 hi; hi.x = P[8 + 2 * q]; hi.y = P[8 + 2 * q + 1];
        *(uint2*)(row + 8 * q + 4 * g) = lo;
        *(uint2*)(row + 32 + 8 * q + 4 * g) = hi;
      }
    }

    tile = ntile;
  }
}

// ---- pass 3: per-node key-max + decode + residual ----
extern "C" __global__ void __launch_bounds__(256)
gather_max_kernel(const float* __restrict__ x, const unsigned short* __restrict__ pmax,
                  const unsigned* __restrict__ base, float* __restrict__ out) {
  const int node = blockIdx.x * 4 + (threadIdx.x >> 6);
  const int lane = threadIdx.x & 63;
  if (node >= NN) return;

  const unsigned b0 = base[node];
  const unsigned b1 = base[node + 1];
  float maxv = 0.f;
  if (b1 > b0) {
    // partial key rows live at position b0 and at each 32-boundary inside (b0, b1)
    unsigned kmax = pmax[(size_t)b0 * 64 + lane];
    const unsigned k1 = (b1 - 1) >> 5;
    for (unsigned k = (b0 >> 5) + 1; k <= k1; ++k) {
      kmax = max(kmax, (unsigned)pmax[((size_t)k << 5) * 64 + lane]);
    }
    // decode monotone key -> bf16 bits
    const unsigned orig = (kmax & 0x8000u) ? (kmax ^ 0x8000u) : (~kmax & 0xFFFFu);
    maxv = __uint_as_float(orig << 16);
  }
  const size_t o = (size_t)node * 64 + lane;
  out[o] = maxv + x[o];
}

extern "C" void kernel_launch(void* const* d_in, const int* in_sizes, int n_in,
                              void* d_out, int out_size, void* d_ws, size_t ws_size,
                              hipStream_t stream) {
  (void)in_sizes; (void)n_in; (void)out_size; (void)ws_size;
  const float* x  = (const float*)d_in[0];
  const float* ew = (const float*)d_in[1];
  const int*   ei = (const int*)d_in[2];
  const float* w1 = (const float*)d_in[3];
  const float* w2 = (const float*)d_in[4];
  const float* w3 = (const float*)d_in[5];
  const float* g1 = (const float*)d_in[6];
  const float* b1 = (const float*)d_in[7];
  const float* g2 = (const float*)d_in[8];
  const float* b2 = (const float*)d_in[9];
  const float* g3 = (const float*)d_in[10];
  const float* b3 = (const float*)d_in[11];

  unsigned* cnt  = (unsigned*)((char*)d_ws + CNT_OFF);
  unsigned* base = (unsigned*)((char*)d_ws + BASE_OFF);
  unsigned* part = (unsigned*)((char*)d_ws + PART_OFF);
  unsigned* slot = (unsigned*)((char*)d_ws + SLOT_OFF);
  uint2*    srcw = (uint2*)((char*)d_ws + SRCW_OFF);
  unsigned short* pmax = (unsigned short*)((char*)d_ws + M_OFF);

  hipMemsetAsync(cnt, 0, (size_t)NN * sizeof(unsigned), stream);
  scatter_kernel<<<(NE + 255) / 256, 256, 0, stream>>>(ei, cnt, slot);
  scan_a_kernel<<<PB, 256, 0, stream>>>(cnt, part);
  scan_c_kernel<<<PB, 256, 0, stream>>>(cnt, part, base);
  reorder_kernel<<<(NE + 255) / 256, 256, 0, stream>>>(ei, ew, base, slot, srcw);
  // grid 3125: 12500 waves -> exactly 2 tiles/wave (zero stride imbalance)
  edge_mlp_kernel<<<3125, 256, 0, stream>>>(x, w1, w2, w3,
                                            g1, b1, g2, b2, g3, b3,
                                            srcw, pmax);
  gather_max_kernel<<<(NN + 3) / 4, 256, 0, stream>>>(x, pmax, base, (float*)d_out);
}